// Round 1
// 961.305 us; speedup vs baseline: 1.0846x; 1.0846x over previous
//
#include <hip/hip_runtime.h>

#define VOCAB 32000
#define NTOK 2048
#define IGNORE_INDEX (-100)

typedef unsigned short u16;
typedef unsigned int u32;
typedef __bf16 bf16x8 __attribute__((ext_vector_type(8)));
typedef float floatx4 __attribute__((ext_vector_type(4)));

__device__ __forceinline__ u16 f2bf(float f) {
    u32 u = __float_as_uint(f);
    u32 r = u + 0x7fffu + ((u >> 16) & 1u);  // round-to-nearest-even
    return (u16)(r >> 16);
}
__device__ __forceinline__ float bf2f(u32 lo16) {
    return __uint_as_float(lo16 << 16);
}

// ---------------- fp32 -> bf16 conversion ----------------
__global__ __launch_bounds__(256) void cvt_kernel(const float* __restrict__ in,
                                                  u16* __restrict__ out, int n4) {
    int i = blockIdx.x * 256 + threadIdx.x;
    if (i >= n4) return;
    float4 v = ((const float4*)in)[i];
    ushort4 o;
    o.x = f2bf(v.x); o.y = f2bf(v.y); o.z = f2bf(v.z); o.w = f2bf(v.w);
    ((ushort4*)out)[i] = o;
}

__global__ __launch_bounds__(256) void zero_kernel(float* __restrict__ p, int n) {
    int i = blockIdx.x * 256 + threadIdx.x;
    if (i < n) p[i] = 0.f;
}

// ---------------- bf16 GEMM (NT), 256x256 tile, 8-phase pipelined ----------------
// 8 waves (2M x 4N), per-wave 128x64 output, BK=64, double-buffered 128 KiB LDS.
// K-loop: per K-step 4 phases of {ds_read subtile | prefetch-issue | s_barrier |
// lgkmcnt(0) | setprio(1) 16xMFMA setprio(0) | s_barrier}; single vmcnt(0) at
// phase-4 start (issued-early / waited-late: ~2 phases of latency cover).
// LDS swizzle: 16B chunk ^ (row&7) via pre-swizzled global source (rule 21);
// measured conflict-free on the 128^2 predecessor (SQ_LDS_BANK_CONFLICT = 0).
// Epilogue: acc -> LDS (256x256 bf16 = exactly 128 KiB, chunk^(row&31) swizzle)
// -> coalesced dwordx4 stores + fused per-row sum(exp(logit)) -> one atomicAdd
// per row per block into rowsum[] (softmax pass 1 fused).
__global__ __launch_bounds__(512, 2) void gemm_bt_kernel(
    const u16* __restrict__ A, const u16* __restrict__ B, u16* __restrict__ C,
    float* __restrict__ rowsum, int M, int N, int K)
{
    __shared__ u16 lds[65536];  // A[2][256][64] | B[2][256][64]; reused as C[256][256]

    const int tid  = threadIdx.x;
    const int lane = tid & 63;
    const int wave = tid >> 6;
    const int wr = wave >> 2;   // 0..1  (M half)
    const int wc = wave & 3;    // 0..3  (N quarter)

    // T1: bijective XCD swizzle (nwg = 1000 = 8*125); m-tile fastest inside a chunk
    const int nx = gridDim.x >> 3;                       // 125 blocks per XCD
    const int wg = (blockIdx.x & 7) * nx + (blockIdx.x >> 3);
    const int bm = (wg & 7) * 256;                       // M = 2048 -> 8 tiles
    const int bn = (wg >> 3) * 256;                      // V = 32000 -> 125 tiles

    const int nk = K >> 6;

    // ---- staging sources (global chunk pre-swizzled: chunk ^ (row&7))
    const int l8 = lane >> 3, c8 = lane & 7;
    const u16* ap[4]; const u16* bp[4];
#pragma unroll
    for (int h = 0; h < 2; ++h)
#pragma unroll
        for (int qq = 0; qq < 2; ++qq) {
            const int r = h * 128 + qq * 64 + wave * 8 + l8;
            ap[h * 2 + qq] = A + (size_t)(bm + r) * K + ((c8 ^ l8) << 3);
            bp[h * 2 + qq] = B + (size_t)(bn + r) * K + ((c8 ^ l8) << 3);
        }
    const int du = wave * 512;  // wave-uniform LDS dest base (u16), hw adds lane*16B

#define GLDS(gp, off) __builtin_amdgcn_global_load_lds( \
        (const __attribute__((address_space(1))) u32*)(gp), \
        (__attribute__((address_space(3))) u32*)(lds + (off)), 16, 0, 0)
#define STAGE_A(b) do { \
        GLDS(ap[0], (b) * 16384 + du);          GLDS(ap[1], (b) * 16384 + 4096 + du); \
        GLDS(ap[2], (b) * 16384 + 8192 + du);   GLDS(ap[3], (b) * 16384 + 12288 + du); \
        ap[0] += 64; ap[1] += 64; ap[2] += 64; ap[3] += 64; } while (0)
#define STAGE_B(b) do { \
        GLDS(bp[0], 32768 + (b) * 16384 + du);        GLDS(bp[1], 32768 + (b) * 16384 + 4096 + du); \
        GLDS(bp[2], 32768 + (b) * 16384 + 8192 + du); GLDS(bp[3], 32768 + (b) * 16384 + 12288 + du); \
        bp[0] += 64; bp[1] += 64; bp[2] += 64; bp[3] += 64; } while (0)

#define BAR()        __builtin_amdgcn_s_barrier()
#define WAIT_LGKM0() asm volatile("s_waitcnt lgkmcnt(0)" ::: "memory")
#define WAIT_VM0()   asm volatile("s_waitcnt vmcnt(0)" ::: "memory")
#define PIN()        __builtin_amdgcn_sched_barrier(0)

    floatx4 acc[8][4] = {};
    bf16x8 af[4][2], bqA[2][2], bqB[2][2];

    const int rA  = wr * 128 + (lane & 15);   // A row base within tile
    const int rB  = wc * 64 + (lane & 15);    // B row base within tile
    const int sw0 = (((lane >> 4) + 0) ^ (lane & 7)) << 3;   // ksub 0 phys chunk
    const int sw1 = (((lane >> 4) + 4) ^ (lane & 7)) << 3;   // ksub 1 phys chunk

    // prologue: stage K-step 0 into buffer 0, full drain once
    STAGE_A(0); STAGE_B(0);
    WAIT_VM0(); BAR();

    for (int ks = 0; ks < nk; ++ks) {
        const int cb = ks & 1;
        const u16* As = lds + cb * 16384;
        const u16* Bs = lds + 32768 + cb * 16384;
        const bool pf = (ks + 1) < nk;   // wave-uniform

        // ---------- phase 1: m0-3 x n0-1 (12 ds_read; issue A prefetch)
#pragma unroll
        for (int m = 0; m < 4; ++m) {
            af[m][0] = *(const bf16x8*)(As + (rA + m * 16) * 64 + sw0);
            af[m][1] = *(const bf16x8*)(As + (rA + m * 16) * 64 + sw1);
        }
#pragma unroll
        for (int n = 0; n < 2; ++n) {
            bqA[n][0] = *(const bf16x8*)(Bs + (rB + n * 16) * 64 + sw0);
            bqA[n][1] = *(const bf16x8*)(Bs + (rB + n * 16) * 64 + sw1);
        }
        if (pf) STAGE_A(cb ^ 1);
        BAR();
        WAIT_LGKM0(); PIN();
        __builtin_amdgcn_s_setprio(1);
#pragma unroll
        for (int m = 0; m < 4; ++m)
#pragma unroll
            for (int n = 0; n < 2; ++n) {
                acc[m][n] = __builtin_amdgcn_mfma_f32_16x16x32_bf16(af[m][0], bqA[n][0], acc[m][n], 0, 0, 0);
                acc[m][n] = __builtin_amdgcn_mfma_f32_16x16x32_bf16(af[m][1], bqA[n][1], acc[m][n], 0, 0, 0);
            }
        __builtin_amdgcn_s_setprio(0);
        BAR();

        // ---------- phase 2: m0-3 x n2-3 (4 ds_read; issue B prefetch)
#pragma unroll
        for (int n = 0; n < 2; ++n) {
            bqB[n][0] = *(const bf16x8*)(Bs + (rB + 32 + n * 16) * 64 + sw0);
            bqB[n][1] = *(const bf16x8*)(Bs + (rB + 32 + n * 16) * 64 + sw1);
        }
        if (pf) STAGE_B(cb ^ 1);
        BAR();
        WAIT_LGKM0(); PIN();
        __builtin_amdgcn_s_setprio(1);
#pragma unroll
        for (int m = 0; m < 4; ++m)
#pragma unroll
            for (int n = 0; n < 2; ++n) {
                acc[m][n + 2] = __builtin_amdgcn_mfma_f32_16x16x32_bf16(af[m][0], bqB[n][0], acc[m][n + 2], 0, 0, 0);
                acc[m][n + 2] = __builtin_amdgcn_mfma_f32_16x16x32_bf16(af[m][1], bqB[n][1], acc[m][n + 2], 0, 0, 0);
            }
        __builtin_amdgcn_s_setprio(0);
        BAR();

        // ---------- phase 3: m4-7 x n0-1 (8 ds_read)
#pragma unroll
        for (int m = 0; m < 4; ++m) {
            af[m][0] = *(const bf16x8*)(As + (rA + 64 + m * 16) * 64 + sw0);
            af[m][1] = *(const bf16x8*)(As + (rA + 64 + m * 16) * 64 + sw1);
        }
        BAR();
        WAIT_LGKM0(); PIN();
        __builtin_amdgcn_s_setprio(1);
#pragma unroll
        for (int m = 0; m < 4; ++m)
#pragma unroll
            for (int n = 0; n < 2; ++n) {
                acc[m + 4][n] = __builtin_amdgcn_mfma_f32_16x16x32_bf16(af[m][0], bqA[n][0], acc[m + 4][n], 0, 0, 0);
                acc[m + 4][n] = __builtin_amdgcn_mfma_f32_16x16x32_bf16(af[m][1], bqA[n][1], acc[m + 4][n], 0, 0, 0);
            }
        __builtin_amdgcn_s_setprio(0);
        BAR();

        // ---------- phase 4: m4-7 x n2-3 (drain prefetch: issued >=2 phases ago)
        WAIT_VM0();
        BAR();
        __builtin_amdgcn_s_setprio(1);
#pragma unroll
        for (int m = 0; m < 4; ++m)
#pragma unroll
            for (int n = 0; n < 2; ++n) {
                acc[m + 4][n + 2] = __builtin_amdgcn_mfma_f32_16x16x32_bf16(af[m][0], bqB[n][0], acc[m + 4][n + 2], 0, 0, 0);
                acc[m + 4][n + 2] = __builtin_amdgcn_mfma_f32_16x16x32_bf16(af[m][1], bqB[n][1], acc[m + 4][n + 2], 0, 0, 0);
            }
        __builtin_amdgcn_s_setprio(0);
        BAR();
    }

    // ---- epilogue: transpose through LDS, coalesced stores, fused sumexp
    // C/D layout: col = lane&15 (+n*16), row = (lane>>4)*4 + reg (+m*16)  [m89/m91]
    __syncthreads();
    const int q4 = lane >> 4;
    const int cl = lane & 15;
#pragma unroll
    for (int m = 0; m < 8; ++m)
#pragma unroll
        for (int n = 0; n < 4; ++n) {
            const int col = wc * 64 + n * 16 + cl;
#pragma unroll
            for (int rr = 0; rr < 4; ++rr) {
                const int row = wr * 128 + m * 16 + q4 * 4 + rr;
                lds[row * 256 + ((((col >> 3) ^ (row & 31)) << 3) | (col & 7))] =
                    f2bf(acc[m][n][rr]);
            }
        }
    __syncthreads();

#pragma unroll
    for (int p = 0; p < 16; ++p) {
        const int idx = p * 512 + tid;
        const int row = idx >> 5;         // 0..255
        const int ch  = idx & 31;         // 16B chunk within 512B row
        uint4 v = *(const uint4*)(lds + row * 256 + ((ch ^ (row & 31)) << 3));
        *(uint4*)(C + (size_t)(bm + row) * N + bn + ch * 8) = v;
        float se = __expf(bf2f(v.x & 0xffffu)) + __expf(bf2f(v.x >> 16))
                 + __expf(bf2f(v.y & 0xffffu)) + __expf(bf2f(v.y >> 16))
                 + __expf(bf2f(v.z & 0xffffu)) + __expf(bf2f(v.z >> 16))
                 + __expf(bf2f(v.w & 0xffffu)) + __expf(bf2f(v.w >> 16));
        se += __shfl_xor(se, 1);
        se += __shfl_xor(se, 2);
        se += __shfl_xor(se, 4);
        se += __shfl_xor(se, 8);
        se += __shfl_xor(se, 16);
        if ((tid & 31) == 0) atomicAdd(rowsum + bm + row, se);
    }
}

// ---------------- single-pass JSD + NLL (lse from fused rowsum) ----------------
__global__ __launch_bounds__(256) void rowstats_kernel(
    const u16* __restrict__ Ls, const u16* __restrict__ Lt,
    const float* __restrict__ rowsum, const int* __restrict__ tgt,
    float* __restrict__ rows)
{
    const int n    = blockIdx.x;
    const int tid  = threadIdx.x;
    const int lane = tid & 63;
    const int wave = tid >> 6;

    const u16* lsrow = Ls + (size_t)n * VOCAB;
    const u16* ltrow = Lt + (size_t)n * VOCAB;
    const uint4* ls4 = (const uint4*)lsrow;
    const uint4* lt4 = (const uint4*)ltrow;
    const int V8 = VOCAB / 8;

    const float lse_s = __logf(rowsum[n]);
    const float lse_t = __logf(rowsum[NTOK + n]);

    float jacc = 0.f;
    for (int v = tid; v < V8; v += 256) {
        uint4 a = ls4[v], b = lt4[v];
        u32 pa[4] = {a.x, a.y, a.z, a.w};
        u32 pb[4] = {b.x, b.y, b.z, b.w};
#pragma unroll
        for (int qq = 0; qq < 4; ++qq) {
            float lsp0 = bf2f(pa[qq] & 0xffffu) - lse_s, lsp1 = bf2f(pa[qq] >> 16) - lse_s;
            float ltp0 = bf2f(pb[qq] & 0xffffu) - lse_t, ltp1 = bf2f(pb[qq] >> 16) - lse_t;
            float sp0 = __expf(lsp0), sp1 = __expf(lsp1);
            float tp0 = __expf(ltp0), tp1 = __expf(ltp1);
            float lm0 = __logf(0.5f * (sp0 + tp0));
            float lm1 = __logf(0.5f * (sp1 + tp1));
            jacc += sp0 * (lsp0 - lm0) + tp0 * (ltp0 - lm0);
            jacc += sp1 * (lsp1 - lm1) + tp1 * (ltp1 - lm1);
        }
    }
#pragma unroll
    for (int off = 32; off > 0; off >>= 1) jacc += __shfl_down(jacc, off);
    __shared__ float jsh[4];
    if (lane == 0) jsh[wave] = jacc;
    __syncthreads();
    if (tid == 0) {
        float j = jsh[0] + jsh[1] + jsh[2] + jsh[3];
        int t = tgt[n];
        bool valid = (t != IGNORE_INDEX);
        float nll = 0.f;
        if (valid) nll = lse_s - bf2f((u32)lsrow[t]);
        rows[n * 3 + 0] = nll;
        rows[n * 3 + 1] = valid ? 1.f : 0.f;
        rows[n * 3 + 2] = j;
    }
}

// ---------------- final scalar reduction ----------------
__global__ __launch_bounds__(256) void final_kernel(const float* __restrict__ rows,
                                                    float* __restrict__ out) {
    const int tid = threadIdx.x;
    float a = 0.f, b = 0.f, c = 0.f;
    for (int i = tid; i < NTOK; i += 256) {
        a += rows[i * 3]; b += rows[i * 3 + 1]; c += rows[i * 3 + 2];
    }
#pragma unroll
    for (int off = 32; off > 0; off >>= 1) {
        a += __shfl_down(a, off);
        b += __shfl_down(b, off);
        c += __shfl_down(c, off);
    }
    __shared__ float sh[4][3];
    const int lane = tid & 63, wave = tid >> 6;
    if (lane == 0) { sh[wave][0] = a; sh[wave][1] = b; sh[wave][2] = c; }
    __syncthreads();
    if (tid == 0) {
        a = sh[0][0] + sh[1][0] + sh[2][0] + sh[3][0];
        b = sh[0][1] + sh[1][1] + sh[2][1] + sh[3][1];
        c = sh[0][2] + sh[1][2] + sh[2][2] + sh[3][2];
        float nv = fmaxf(b, 1.f);
        out[0] = 0.5f * (a / nv) + 0.25f * (c / (float)NTOK);
    }
}

extern "C" void kernel_launch(void* const* d_in, const int* in_sizes, int n_in,
                              void* d_out, int out_size, void* d_ws, size_t ws_size,
                              hipStream_t stream)
{
    const float* s_in = (const float*)d_in[0];   // 2048 x 1024
    const float* t_in = (const float*)d_in[1];   // 2048 x 2048
    const float* s_w  = (const float*)d_in[2];   // 32000 x 1024
    const float* t_w  = (const float*)d_in[3];   // 32000 x 2048
    const int*   tgt  = (const int*)d_in[4];     // 2048

    u16* sA = (u16*)d_ws;
    u16* tA = sA + (size_t)NTOK * 1024;
    u16* sW = tA + (size_t)NTOK * 2048;
    u16* tW = sW + (size_t)VOCAB * 1024;
    u16* Ls = tW + (size_t)VOCAB * 2048;
    u16* Lt = Ls + (size_t)NTOK * VOCAB;
    float* rows   = (float*)(Lt + (size_t)NTOK * VOCAB);
    float* rowsum = rows + NTOK * 3;             // [0..NTOK): student, [NTOK..2N): teacher

    int n4;
    n4 = NTOK * 1024 / 4;  cvt_kernel<<<(n4 + 255) / 256, 256, 0, stream>>>(s_in, sA, n4);
    n4 = NTOK * 2048 / 4;  cvt_kernel<<<(n4 + 255) / 256, 256, 0, stream>>>(t_in, tA, n4);
    n4 = VOCAB * 1024 / 4; cvt_kernel<<<(n4 + 255) / 256, 256, 0, stream>>>(s_w, sW, n4);
    n4 = VOCAB * 2048 / 4; cvt_kernel<<<(n4 + 255) / 256, 256, 0, stream>>>(t_w, tW, n4);
    zero_kernel<<<(2 * NTOK + 255) / 256, 256, 0, stream>>>(rowsum, 2 * NTOK);

    // 256^2 tiles: (2048/256) * (32000/256) = 8 * 125 = 1000 workgroups
    gemm_bt_kernel<<<dim3(1000), 512, 0, stream>>>(sA, sW, Ls, rowsum,        NTOK, VOCAB, 1024);
    gemm_bt_kernel<<<dim3(1000), 512, 0, stream>>>(tA, tW, Lt, rowsum + NTOK, NTOK, VOCAB, 2048);

    rowstats_kernel<<<NTOK, 256, 0, stream>>>(Ls, Lt, rowsum, tgt, rows);
    final_kernel<<<1, 256, 0, stream>>>(rows, (float*)d_out);
}